// Round 10
// baseline (234.350 us; speedup 1.0000x reference)
//
#include <hip/hip_runtime.h>

// ConvCapsuleLayer: B=2, 48x48, IN_CAPS=8, ATOMS=16, KER=3, OUT_CAPS=16, R=3.
// Round-21 (final): r19 base (best measured, 42.0us/dispatch) + two latency
// cuts, zero layout changes:
//  - ALL explicit lgkmcnt(0) fences DELETED. Rationale: this kernel has zero
//    cross-wave dependencies; DS ops from one wave execute in-order at the
//    LDS pipe (LLVM's memory model emits nothing for wavefront-scope LDS
//    fences; compiler preserves program order for may-alias DS ops and
//    auto-waits on read-result uses). The fences were pure idle (~1K
//    cyc/pixel) plus scheduler barriers blocking G-store/GDOT-load overlap.
//  - Tree reductions: squash square-sum, softmax fmax, softmax sum go from
//    15-16-deep serial chains to depth-4-5 binary trees (same op count).
// r20 post-mortem: fp16 pose regressed (cvt lengthened chains; LDS-throughput
// model falsified) -> reverted to fp32 everywhere.
// Keeps: zero-barrier wave-per-pixel, coup aliased into G (all G reads before
// CP writes), e'=b*4+a G packing, hoisted pose columns, XCD chunk swizzle,
// r0 act specialization, stride-20+skew layouts.
// Guard: WRITE_SIZE ~4.2MB (no spill), FETCH ~1.5MB.

#define NPIX 4232
#define NBLK 2116   // 2 pixels/block, 1 per wave

typedef float v2f __attribute__((ext_vector_type(2)));
typedef float v4f __attribute__((ext_vector_type(4)));

__device__ __forceinline__ v2f lo2(v4f v) { return __builtin_shufflevector(v, v, 0, 1); }
__device__ __forceinline__ v2f hi2(v4f v) { return __builtin_shufflevector(v, v, 2, 3); }
__device__ __forceinline__ v2f fma2(v2f a, v2f b, v2f c) {
    return __builtin_elementwise_fma(a, b, c);
}

template<int CTRL>
__device__ __forceinline__ float dpp_f(float x) {
    return __int_as_float(
        __builtin_amdgcn_update_dpp(0, __float_as_int(x), CTRL, 0xF, 0xF, true));
}
template<int OFF>
__device__ __forceinline__ float swz(float x) {
    return __int_as_float(__builtin_amdgcn_ds_swizzle(__float_as_int(x), OFF));
}

// G row start for (o, ic): stride 20 rows + 4*o skew (round-11 verified).
__device__ __forceinline__ int g_row(int o, int ic) {
    return (o * 8 + ic) * 20 + o * 4;
}

__global__ __launch_bounds__(128, 2)
void capsule_routing_kernel(const float* __restrict__ x,
                            const float* __restrict__ Wg,
                            float* __restrict__ out)
{
    // per-pixel: pose_t [aa][k] stride 76 (1216) + act[72] @1216 -> 1288
    //            GB: G (2616 floats) with coup ALIASED at GB[0..1216)
    __shared__ alignas(16) float pose_t[2][1288];   // 10304 B
    __shared__ alignas(16) float g_buf[2][2616];    // 20928 B
    // total 31232 B -> 5 blocks/CU (10 independent waves)

    const int tid  = threadIdx.x;
    const int wid  = tid >> 6;
    const int lane = tid & 63;
    const int o    = lane >> 2;
    const int cq   = lane & 3;

    float* PT = pose_t[wid];
    float* GB = g_buf[wid];

    // bijective chunked XCD swizzle over 2116 workgroups (q=264, r=4)
    const int bx  = blockIdx.x;
    const int xcd = bx & 7;
    const int sub = bx >> 3;
    const int wgs = (xcd < 4 ? xcd * 265 : 1060 + (xcd - 4) * 264) + sub;
    const int n   = wgs * 2 + wid;

    const int b   = n / (46 * 46);
    const int rem = n - b * (46 * 46);
    const int ho  = rem / 46;
    const int wo  = rem - ho * 46;

    // ---- W row fragment: w01[ic]=(W[ic][o][cq][0],[1]), w23=([2],[3]) ----
    v2f w01[8], w23[8];
    #pragma unroll
    for (int i = 0; i < 8; ++i) {
        const v4f wv = *reinterpret_cast<const v4f*>(
            &Wg[((i * 16 + o) * 4 + cq) * 4]);
        w01[i] = lo2(wv);
        w23[i] = hi2(wv);
    }

    // ---- wave-local load of this pixel's 3x3 patch (9 x 136 ch) ----
    // (DS ops are per-wave in-order: the hoisted column reads below are
    //  ordered after these writes by HW; no explicit fence needed.)
    #pragma unroll
    for (int p = 0; p < 9; ++p) {
        const int py = p / 3, px = p - py * 3;
        const float* xr = &x[(((b * 48) + ho + py) * 48 + (wo + px)) * 136];
        #pragma unroll
        for (int t = 0; t < 3; ++t) {
            const int cc = lane + t * 64;
            if (t < 2 || cc < 136) {
                const float val = xr[cc];
                const int ic = (cc * 241) >> 12;       // cc/17 for cc<136
                const int aa = cc - ic * 17;
                const int k  = p * 8 + ic;
                if (aa == 16) PT[1216 + k] = val;      // act
                else          PT[aa * 76 + k] = val;
            }
        }
    }

    const int kT  = 64 + (lane >> 3);
    const int icT = lane >> 3;         // = kT & 7
    const int oT0 = (lane & 7) * 2;
    const int icM = lane & 7;

    // ---- round-invariant pose columns + act, hoisted (registers) ----
    float pc[16], pcT[16];
    #pragma unroll
    for (int j = 0; j < 16; ++j) pc[j]  = PT[j * 76 + lane];
    #pragma unroll
    for (int j = 0; j < 16; ++j) pcT[j] = PT[j * 76 + kT];
    const float actk = PT[1216 + lane];
    const float actT = PT[1216 + kT];

    float lreg[16];
    #pragma unroll
    for (int j = 0; j < 16; ++j) lreg[j] = 0.f;
    float lt0 = 0.f, lt1 = 0.f;

    v2f va01[4], va23[4];              // squashed v[o][a][j], full per lane

    // dot of a pose-column (16 regs) against one G' row (4 chunks, e'=b*4+a)
    #define GDOT(P, gp, accum) do {                                          \
        const v4f b0 = (gp)[0], b1 = (gp)[1], b2 = (gp)[2], b3 = (gp)[3];    \
        v2f acc2 = {0.f, 0.f};                                               \
        acc2 = fma2(v2f{(P)[0], (P)[4]},  lo2(b0), acc2);                    \
        acc2 = fma2(v2f{(P)[8], (P)[12]}, hi2(b0), acc2);                    \
        acc2 = fma2(v2f{(P)[1], (P)[5]},  lo2(b1), acc2);                    \
        acc2 = fma2(v2f{(P)[9], (P)[13]}, hi2(b1), acc2);                    \
        acc2 = fma2(v2f{(P)[2], (P)[6]},  lo2(b2), acc2);                    \
        acc2 = fma2(v2f{(P)[10],(P)[14]}, hi2(b2), acc2);                    \
        acc2 = fma2(v2f{(P)[3], (P)[7]},  lo2(b3), acc2);                    \
        acc2 = fma2(v2f{(P)[11],(P)[15]}, hi2(b3), acc2);                    \
        accum += acc2.x + acc2.y;                                            \
    } while (0)

    #pragma unroll 1
    for (int r = 0; r < 3; ++r) {
        // ---- phase B: M[ic][a] = sum_p coup[8p+ic][o] * pose[8p+ic][a4+cq]
        const float* cb  = (r == 0) ? (PT + 1216) : (GB + o * 76);
        const float  msc = (r == 0) ? 0.0625f : 1.0f;
        v2f mac[4][4];   // [ic-pair][a]
        #pragma unroll
        for (int m = 0; m < 4; ++m)
            #pragma unroll
            for (int a = 0; a < 4; ++a) mac[m][a] = v2f{0.f, 0.f};
        #pragma unroll
        for (int p = 0; p < 9; ++p) {
            const v4f c0 = *reinterpret_cast<const v4f*>(cb + 8 * p);
            const v4f c1 = *reinterpret_cast<const v4f*>(cb + 8 * p + 4);
            #pragma unroll
            for (int a = 0; a < 4; ++a) {
                const v4f q0 = *reinterpret_cast<const v4f*>(
                    &PT[(a * 4 + cq) * 76 + 8 * p]);
                const v4f q1 = *reinterpret_cast<const v4f*>(
                    &PT[(a * 4 + cq) * 76 + 8 * p + 4]);
                mac[0][a] = fma2(lo2(c0), lo2(q0), mac[0][a]);
                mac[1][a] = fma2(hi2(c0), hi2(q0), mac[1][a]);
                mac[2][a] = fma2(lo2(c1), lo2(q1), mac[2][a]);
                mac[3][a] = fma2(hi2(c1), hi2(q1), mac[3][a]);
            }
        }
        // U[a][j] = sum_ic W[ic,o,cq,j] * M[ic][a]
        v2f U01[4], U23[4];
        #pragma unroll
        for (int a = 0; a < 4; ++a) { U01[a] = v2f{0.f,0.f}; U23[a] = v2f{0.f,0.f}; }
        #pragma unroll
        for (int m = 0; m < 4; ++m) {
            #pragma unroll
            for (int a = 0; a < 4; ++a) {
                const v2f m0 = { mac[m][a].x, mac[m][a].x };
                const v2f m1 = { mac[m][a].y, mac[m][a].y };
                U01[a] = fma2(w01[2*m],   m0, U01[a]);
                U23[a] = fma2(w23[2*m],   m0, U23[a]);
                U01[a] = fma2(w01[2*m+1], m1, U01[a]);
                U23[a] = fma2(w23[2*m+1], m1, U23[a]);
            }
        }
        // quad allreduce over cq (=b): Z[a*4+j] = s[o,a,j]
        float Z[16];
        #pragma unroll
        for (int a = 0; a < 4; ++a) {
            Z[a*4+0] = U01[a].x * msc;  Z[a*4+1] = U01[a].y * msc;
            Z[a*4+2] = U23[a].x * msc;  Z[a*4+3] = U23[a].y * msc;
        }
        #pragma unroll
        for (int j = 0; j < 16; ++j) {
            Z[j] += dpp_f<0xB1>(Z[j]);
            Z[j] += dpp_f<0x4E>(Z[j]);
        }
        // squash: lane-local, tree square-sum (depth ~5, was 16)
        float sq;
        {
            float t8[8];
            #pragma unroll
            for (int j = 0; j < 8; ++j)
                t8[j] = fmaf(Z[2*j+1], Z[2*j+1], Z[2*j] * Z[2*j]);
            const float t40 = t8[0] + t8[1], t41 = t8[2] + t8[3];
            const float t42 = t8[4] + t8[5], t43 = t8[6] + t8[7];
            sq = (t40 + t41) + (t42 + t43);
        }
        const float ss = sq / ((1.f + sq) * sqrtf(sq + 1e-7f));
        #pragma unroll
        for (int a = 0; a < 4; ++a) {
            va01[a] = v2f{ Z[a*4+0] * ss, Z[a*4+1] * ss };
            va23[a] = v2f{ Z[a*4+2] * ss, Z[a*4+3] * ss };
        }

        if (r < 2) {
            // ---- G build, e'=b*4+a packing: one b128 store per ic ----
            // (no fence: same-wave DS in-order; scheduler may overlap these
            //  stores with the GDOT loads below)
            #pragma unroll
            for (int ic = 0; ic < 8; ++ic) {
                v4f gv;
                #pragma unroll
                for (int a = 0; a < 4; ++a) {
                    const v2f h = fma2(w23[ic], va23[a], w01[ic] * va01[a]);
                    gv[a] = h.x + h.y;
                }
                *reinterpret_cast<v4f*>(&GB[g_row(o, ic) + cq * 4]) = gv;
            }

            // ---- fused: ALL G reads first (main + tail), then CP writes ----
            float lg[16];
            #pragma unroll
            for (int oo = 0; oo < 16; ++oo) {
                const v4f* gp = reinterpret_cast<const v4f*>(&GB[g_row(oo, icM)]);
                GDOT(pc, gp, lreg[oo]);
                lg[oo] = lreg[oo];
            }
            {
                const v4f* gp0 = reinterpret_cast<const v4f*>(&GB[g_row(oT0, icT)]);
                GDOT(pcT, gp0, lt0);
                const v4f* gp1 = reinterpret_cast<const v4f*>(&GB[g_row(oT0 + 1, icT)]);
                GDOT(pcT, gp1, lt1);
            }

            // main softmax over 16 o (lane-local), tree max/sum (depth 4)
            float mx;
            {
                float m8[8];
                #pragma unroll
                for (int j = 0; j < 8; ++j) m8[j] = fmaxf(lg[2*j], lg[2*j+1]);
                const float m40 = fmaxf(m8[0], m8[1]), m41 = fmaxf(m8[2], m8[3]);
                const float m42 = fmaxf(m8[4], m8[5]), m43 = fmaxf(m8[6], m8[7]);
                mx = fmaxf(fmaxf(m40, m41), fmaxf(m42, m43));
            }
            #pragma unroll
            for (int j = 0; j < 16; ++j) lg[j] = __expf(lg[j] - mx);
            float sum;
            {
                float s8[8];
                #pragma unroll
                for (int j = 0; j < 8; ++j) s8[j] = lg[2*j] + lg[2*j+1];
                const float s40 = s8[0] + s8[1], s41 = s8[2] + s8[3];
                const float s42 = s8[4] + s8[5], s43 = s8[6] + s8[7];
                sum = (s40 + s41) + (s42 + s43);
            }
            const float cs = actk / sum;
            #pragma unroll
            for (int oo = 0; oo < 16; ++oo) GB[oo * 76 + lane] = lg[oo] * cs;

            // tail softmax over 16 o spread across 8-lane group (2 per lane)
            {
                float m2 = fmaxf(lt0, lt1);
                m2 = fmaxf(m2, swz<0x041F>(m2));
                m2 = fmaxf(m2, swz<0x081F>(m2));
                m2 = fmaxf(m2, swz<0x101F>(m2));
                const float e0 = __expf(lt0 - m2);
                const float e1 = __expf(lt1 - m2);
                float s2 = e0 + e1;
                s2 += swz<0x041F>(s2);
                s2 += swz<0x081F>(s2);
                s2 += swz<0x101F>(s2);
                const float csT = actT / s2;
                GB[oT0 * 76 + kT]       = e0 * csT;
                GB[(oT0 + 1) * 76 + kT] = e1 * csT;
            }
        }
    }

    // ---- out[n][o][e=a*4+cq] = v[a][cq] ----
    #pragma unroll
    for (int a = 0; a < 4; ++a) {
        const float vo = (cq & 2) ? ((cq & 1) ? va23[a].y : va23[a].x)
                                  : ((cq & 1) ? va01[a].y : va01[a].x);
        out[n * 256 + o * 16 + a * 4 + cq] = vo;
    }
}

extern "C" void kernel_launch(void* const* d_in, const int* in_sizes, int n_in,
                              void* d_out, int out_size, void* d_ws, size_t ws_size,
                              hipStream_t stream) {
    const float* x  = (const float*)d_in[0];   // [2,48,48,136] fp32
    const float* Wt = (const float*)d_in[1];   // [8,16,4,4]    fp32
    float* outp = (float*)d_out;               // [2,46,46,16,16] fp32
    capsule_routing_kernel<<<dim3(NBLK), dim3(128), 0, stream>>>(x, Wt, outp);
}

// Round 11
// 90.426 us; speedup vs baseline: 2.5916x; 2.5916x over previous
//
#include <hip/hip_runtime.h>

// ConvCapsuleLayer: B=2, 48x48, IN_CAPS=8, ATOMS=16, KER=3, OUT_CAPS=16, R=3.
// Round-22 (FINAL): byte-for-byte restore of round-19, the session's measured
// best (41.7-42.9 us/dispatch, bench 89.86us).
// r21 post-mortem: deleting the lgkmcnt(0) fences removed the scheduler
// region boundaries they implicitly provided -> compiler fused G-build /
// 18 GDOT chains / softmax / next phase-B into one region, live ranges
// exploded (VGPR 84->128), scratch spills (FETCH 283MB, WRITE 246MB), 4.4x
// slower. The fences stay: they cost ~1K cyc/pixel but bound register
// pressure.
// Falsified-levers ledger (all measured on HW): +residency (r13/14),
// -LDS-traffic (r16), +ILP 2px (r17), fp16 bytes/elem (r20),
// -fences/tree-reductions (r21). r19's latency-bound ~42us is the
// structural floor for this algorithm shape on gfx950.
// Structure: zero-barrier wave-per-pixel; lane=(o,c); quad-allreduce gives
// each lane full s[o,:]; squash+G-build lane-local; coup aliased into G
// (all G reads precede CP writes); e'=b*4+a G packing (b128 stores);
// hoisted round-invariant pose columns; XCD chunk swizzle; r0 act
// specialization.

#define NPIX 4232
#define NBLK 2116   // 2 pixels/block, 1 per wave

typedef float v2f __attribute__((ext_vector_type(2)));
typedef float v4f __attribute__((ext_vector_type(4)));

__device__ __forceinline__ v2f lo2(v4f v) { return __builtin_shufflevector(v, v, 0, 1); }
__device__ __forceinline__ v2f hi2(v4f v) { return __builtin_shufflevector(v, v, 2, 3); }
__device__ __forceinline__ v2f fma2(v2f a, v2f b, v2f c) {
    return __builtin_elementwise_fma(a, b, c);
}

template<int CTRL>
__device__ __forceinline__ float dpp_f(float x) {
    return __int_as_float(
        __builtin_amdgcn_update_dpp(0, __float_as_int(x), CTRL, 0xF, 0xF, true));
}
template<int OFF>
__device__ __forceinline__ float swz(float x) {
    return __int_as_float(__builtin_amdgcn_ds_swizzle(__float_as_int(x), OFF));
}

// G row start for (o, ic): stride 20 rows + 4*o skew (round-11 verified).
__device__ __forceinline__ int g_row(int o, int ic) {
    return (o * 8 + ic) * 20 + o * 4;
}

__global__ __launch_bounds__(128, 2)
void capsule_routing_kernel(const float* __restrict__ x,
                            const float* __restrict__ Wg,
                            float* __restrict__ out)
{
    // per-pixel: pose_t [aa][k] stride 76 (1216) + act[72] @1216 -> 1288
    //            GB: G (2616 floats) with coup ALIASED at GB[0..1216)
    __shared__ alignas(16) float pose_t[2][1288];   // 10304 B
    __shared__ alignas(16) float g_buf[2][2616];    // 20928 B
    // total 31232 B -> 5 blocks/CU (10 independent waves)

    const int tid  = threadIdx.x;
    const int wid  = tid >> 6;
    const int lane = tid & 63;
    const int o    = lane >> 2;
    const int cq   = lane & 3;

    float* PT = pose_t[wid];
    float* GB = g_buf[wid];

    // bijective chunked XCD swizzle over 2116 workgroups (q=264, r=4)
    const int bx  = blockIdx.x;
    const int xcd = bx & 7;
    const int sub = bx >> 3;
    const int wgs = (xcd < 4 ? xcd * 265 : 1060 + (xcd - 4) * 264) + sub;
    const int n   = wgs * 2 + wid;

    const int b   = n / (46 * 46);
    const int rem = n - b * (46 * 46);
    const int ho  = rem / 46;
    const int wo  = rem - ho * 46;

    // ---- W row fragment: w01[ic]=(W[ic][o][cq][0],[1]), w23=([2],[3]) ----
    v2f w01[8], w23[8];
    #pragma unroll
    for (int i = 0; i < 8; ++i) {
        const v4f wv = *reinterpret_cast<const v4f*>(
            &Wg[((i * 16 + o) * 4 + cq) * 4]);
        w01[i] = lo2(wv);
        w23[i] = hi2(wv);
    }

    // ---- wave-local load of this pixel's 3x3 patch (9 x 136 ch) ----
    #pragma unroll
    for (int p = 0; p < 9; ++p) {
        const int py = p / 3, px = p - py * 3;
        const float* xr = &x[(((b * 48) + ho + py) * 48 + (wo + px)) * 136];
        #pragma unroll
        for (int t = 0; t < 3; ++t) {
            const int cc = lane + t * 64;
            if (t < 2 || cc < 136) {
                const float val = xr[cc];
                const int ic = (cc * 241) >> 12;       // cc/17 for cc<136
                const int aa = cc - ic * 17;
                const int k  = p * 8 + ic;
                if (aa == 16) PT[1216 + k] = val;      // act
                else          PT[aa * 76 + k] = val;
            }
        }
    }
    asm volatile("s_waitcnt lgkmcnt(0)" ::: "memory");

    const int kT  = 64 + (lane >> 3);
    const int icT = lane >> 3;         // = kT & 7
    const int oT0 = (lane & 7) * 2;
    const int icM = lane & 7;

    // ---- round-invariant pose columns + act, hoisted (registers) ----
    float pc[16], pcT[16];
    #pragma unroll
    for (int j = 0; j < 16; ++j) pc[j]  = PT[j * 76 + lane];
    #pragma unroll
    for (int j = 0; j < 16; ++j) pcT[j] = PT[j * 76 + kT];
    const float actk = PT[1216 + lane];
    const float actT = PT[1216 + kT];
    asm volatile("s_waitcnt lgkmcnt(0)" ::: "memory");

    float lreg[16];
    #pragma unroll
    for (int j = 0; j < 16; ++j) lreg[j] = 0.f;
    float lt0 = 0.f, lt1 = 0.f;

    v2f va01[4], va23[4];              // squashed v[o][a][j], full per lane

    // dot of a pose-column (16 regs) against one G' row (4 chunks, e'=b*4+a)
    #define GDOT(P, gp, accum) do {                                          \
        const v4f b0 = (gp)[0], b1 = (gp)[1], b2 = (gp)[2], b3 = (gp)[3];    \
        v2f acc2 = {0.f, 0.f};                                               \
        acc2 = fma2(v2f{(P)[0], (P)[4]},  lo2(b0), acc2);                    \
        acc2 = fma2(v2f{(P)[8], (P)[12]}, hi2(b0), acc2);                    \
        acc2 = fma2(v2f{(P)[1], (P)[5]},  lo2(b1), acc2);                    \
        acc2 = fma2(v2f{(P)[9], (P)[13]}, hi2(b1), acc2);                    \
        acc2 = fma2(v2f{(P)[2], (P)[6]},  lo2(b2), acc2);                    \
        acc2 = fma2(v2f{(P)[10],(P)[14]}, hi2(b2), acc2);                    \
        acc2 = fma2(v2f{(P)[3], (P)[7]},  lo2(b3), acc2);                    \
        acc2 = fma2(v2f{(P)[11],(P)[15]}, hi2(b3), acc2);                    \
        accum += acc2.x + acc2.y;                                            \
    } while (0)

    #pragma unroll 1
    for (int r = 0; r < 3; ++r) {
        // ---- phase B: M[ic][a] = sum_p coup[8p+ic][o] * pose[8p+ic][a4+cq]
        const float* cb  = (r == 0) ? (PT + 1216) : (GB + o * 76);
        const float  msc = (r == 0) ? 0.0625f : 1.0f;
        v2f mac[4][4];   // [ic-pair][a]
        #pragma unroll
        for (int m = 0; m < 4; ++m)
            #pragma unroll
            for (int a = 0; a < 4; ++a) mac[m][a] = v2f{0.f, 0.f};
        #pragma unroll
        for (int p = 0; p < 9; ++p) {
            const v4f c0 = *reinterpret_cast<const v4f*>(cb + 8 * p);
            const v4f c1 = *reinterpret_cast<const v4f*>(cb + 8 * p + 4);
            #pragma unroll
            for (int a = 0; a < 4; ++a) {
                const v4f q0 = *reinterpret_cast<const v4f*>(
                    &PT[(a * 4 + cq) * 76 + 8 * p]);
                const v4f q1 = *reinterpret_cast<const v4f*>(
                    &PT[(a * 4 + cq) * 76 + 8 * p + 4]);
                mac[0][a] = fma2(lo2(c0), lo2(q0), mac[0][a]);
                mac[1][a] = fma2(hi2(c0), hi2(q0), mac[1][a]);
                mac[2][a] = fma2(lo2(c1), lo2(q1), mac[2][a]);
                mac[3][a] = fma2(hi2(c1), hi2(q1), mac[3][a]);
            }
        }
        // U[a][j] = sum_ic W[ic,o,cq,j] * M[ic][a]
        v2f U01[4], U23[4];
        #pragma unroll
        for (int a = 0; a < 4; ++a) { U01[a] = v2f{0.f,0.f}; U23[a] = v2f{0.f,0.f}; }
        #pragma unroll
        for (int m = 0; m < 4; ++m) {
            #pragma unroll
            for (int a = 0; a < 4; ++a) {
                const v2f m0 = { mac[m][a].x, mac[m][a].x };
                const v2f m1 = { mac[m][a].y, mac[m][a].y };
                U01[a] = fma2(w01[2*m],   m0, U01[a]);
                U23[a] = fma2(w23[2*m],   m0, U23[a]);
                U01[a] = fma2(w01[2*m+1], m1, U01[a]);
                U23[a] = fma2(w23[2*m+1], m1, U23[a]);
            }
        }
        // quad allreduce over cq (=b): Z[a*4+j] = s[o,a,j]
        float Z[16];
        #pragma unroll
        for (int a = 0; a < 4; ++a) {
            Z[a*4+0] = U01[a].x * msc;  Z[a*4+1] = U01[a].y * msc;
            Z[a*4+2] = U23[a].x * msc;  Z[a*4+3] = U23[a].y * msc;
        }
        #pragma unroll
        for (int j = 0; j < 16; ++j) {
            Z[j] += dpp_f<0xB1>(Z[j]);
            Z[j] += dpp_f<0x4E>(Z[j]);
        }
        // squash: fully lane-local
        float sq = 0.f;
        #pragma unroll
        for (int j = 0; j < 16; ++j) sq = fmaf(Z[j], Z[j], sq);
        const float ss = sq / ((1.f + sq) * sqrtf(sq + 1e-7f));
        #pragma unroll
        for (int a = 0; a < 4; ++a) {
            va01[a] = v2f{ Z[a*4+0] * ss, Z[a*4+1] * ss };
            va23[a] = v2f{ Z[a*4+2] * ss, Z[a*4+3] * ss };
        }

        if (r < 2) {
            // ---- G build, e'=b*4+a packing: one b128 store per ic ----
            #pragma unroll
            for (int ic = 0; ic < 8; ++ic) {
                v4f gv;
                #pragma unroll
                for (int a = 0; a < 4; ++a) {
                    const v2f h = fma2(w23[ic], va23[a], w01[ic] * va01[a]);
                    gv[a] = h.x + h.y;
                }
                *reinterpret_cast<v4f*>(&GB[g_row(o, ic) + cq * 4]) = gv;
            }
            asm volatile("s_waitcnt lgkmcnt(0)" ::: "memory");

            // ---- fused: ALL G reads first (main + tail), then CP writes ----
            float lg[16];
            #pragma unroll
            for (int oo = 0; oo < 16; ++oo) {
                const v4f* gp = reinterpret_cast<const v4f*>(&GB[g_row(oo, icM)]);
                GDOT(pc, gp, lreg[oo]);
                lg[oo] = lreg[oo];
            }
            {
                const v4f* gp0 = reinterpret_cast<const v4f*>(&GB[g_row(oT0, icT)]);
                GDOT(pcT, gp0, lt0);
                const v4f* gp1 = reinterpret_cast<const v4f*>(&GB[g_row(oT0 + 1, icT)]);
                GDOT(pcT, gp1, lt1);
            }

            // main softmax over 16 o (lane-local) -> CP writes (alias GB)
            float mx = lg[0];
            #pragma unroll
            for (int j = 1; j < 16; ++j) mx = fmaxf(mx, lg[j]);
            float sum = 0.f;
            #pragma unroll
            for (int j = 0; j < 16; ++j) { lg[j] = __expf(lg[j] - mx); sum += lg[j]; }
            const float cs = actk / sum;
            #pragma unroll
            for (int oo = 0; oo < 16; ++oo) GB[oo * 76 + lane] = lg[oo] * cs;

            // tail softmax over 16 o spread across 8-lane group (2 per lane)
            {
                float m2 = fmaxf(lt0, lt1);
                m2 = fmaxf(m2, swz<0x041F>(m2));
                m2 = fmaxf(m2, swz<0x081F>(m2));
                m2 = fmaxf(m2, swz<0x101F>(m2));
                const float e0 = __expf(lt0 - m2);
                const float e1 = __expf(lt1 - m2);
                float s2 = e0 + e1;
                s2 += swz<0x041F>(s2);
                s2 += swz<0x081F>(s2);
                s2 += swz<0x101F>(s2);
                const float csT = actT / s2;
                GB[oT0 * 76 + kT]       = e0 * csT;
                GB[(oT0 + 1) * 76 + kT] = e1 * csT;
            }
            asm volatile("s_waitcnt lgkmcnt(0)" ::: "memory");
        }
    }

    // ---- out[n][o][e=a*4+cq] = v[a][cq] ----
    #pragma unroll
    for (int a = 0; a < 4; ++a) {
        const float vo = (cq & 2) ? ((cq & 1) ? va23[a].y : va23[a].x)
                                  : ((cq & 1) ? va01[a].y : va01[a].x);
        out[n * 256 + o * 16 + a * 4 + cq] = vo;
    }
}

extern "C" void kernel_launch(void* const* d_in, const int* in_sizes, int n_in,
                              void* d_out, int out_size, void* d_ws, size_t ws_size,
                              hipStream_t stream) {
    const float* x  = (const float*)d_in[0];   // [2,48,48,136] fp32
    const float* Wt = (const float*)d_in[1];   // [8,16,4,4]    fp32
    float* outp = (float*)d_out;               // [2,46,46,16,16] fp32
    capsule_routing_kernel<<<dim3(NBLK), dim3(128), 0, stream>>>(x, Wt, outp);
}

// Round 12
// 90.180 us; speedup vs baseline: 2.5987x; 1.0027x over previous
//
#include <hip/hip_runtime.h>

// ConvCapsuleLayer: B=2, 48x48, IN_CAPS=8, ATOMS=16, KER=3, OUT_CAPS=16, R=3.
// Round-23: r19/r22 base (measured best: 41.2-41.4us steady, bench 89.9-90.4)
// + ONE micro-fix: coalesced b128 epilogue store.
//   Z is quad-allreduced -> every lane of a quad holds the full v[o][a][j],
//   so lane (o,cq) writes atoms (a'=cq, j=0..3) as one aligned b128 at
//   base + lane*16B: a single fully-coalesced 1024B wave store, replacing
//   4 quarter-coalesced b32 stores (same cndmask count, -3 store instrs).
// Falsified-levers ledger (all measured on HW): +residency (r13/14),
// -LDS-traffic (r16), +ILP 2px (r17), fp16 bytes/elem (r20), -fences/tree
// reductions (r21 -> spill catastrophe; fences bound regalloc regions).
// Structure: zero-barrier wave-per-pixel; lane=(o,c); quad-allreduce gives
// each lane full s[o,:]; squash+G-build lane-local; coup aliased into G
// (all G reads precede CP writes); e'=b*4+a G packing (b128 stores);
// hoisted round-invariant pose columns; XCD chunk swizzle; r0 act
// specialization. Guard: WRITE_SIZE ~4.2MB (no spill), FETCH ~1.5MB.

#define NPIX 4232
#define NBLK 2116   // 2 pixels/block, 1 per wave

typedef float v2f __attribute__((ext_vector_type(2)));
typedef float v4f __attribute__((ext_vector_type(4)));

__device__ __forceinline__ v2f lo2(v4f v) { return __builtin_shufflevector(v, v, 0, 1); }
__device__ __forceinline__ v2f hi2(v4f v) { return __builtin_shufflevector(v, v, 2, 3); }
__device__ __forceinline__ v2f fma2(v2f a, v2f b, v2f c) {
    return __builtin_elementwise_fma(a, b, c);
}

template<int CTRL>
__device__ __forceinline__ float dpp_f(float x) {
    return __int_as_float(
        __builtin_amdgcn_update_dpp(0, __float_as_int(x), CTRL, 0xF, 0xF, true));
}
template<int OFF>
__device__ __forceinline__ float swz(float x) {
    return __int_as_float(__builtin_amdgcn_ds_swizzle(__float_as_int(x), OFF));
}

// G row start for (o, ic): stride 20 rows + 4*o skew (round-11 verified).
__device__ __forceinline__ int g_row(int o, int ic) {
    return (o * 8 + ic) * 20 + o * 4;
}

__global__ __launch_bounds__(128, 2)
void capsule_routing_kernel(const float* __restrict__ x,
                            const float* __restrict__ Wg,
                            float* __restrict__ out)
{
    // per-pixel: pose_t [aa][k] stride 76 (1216) + act[72] @1216 -> 1288
    //            GB: G (2616 floats) with coup ALIASED at GB[0..1216)
    __shared__ alignas(16) float pose_t[2][1288];   // 10304 B
    __shared__ alignas(16) float g_buf[2][2616];    // 20928 B
    // total 31232 B -> 5 blocks/CU (10 independent waves)

    const int tid  = threadIdx.x;
    const int wid  = tid >> 6;
    const int lane = tid & 63;
    const int o    = lane >> 2;
    const int cq   = lane & 3;

    float* PT = pose_t[wid];
    float* GB = g_buf[wid];

    // bijective chunked XCD swizzle over 2116 workgroups (q=264, r=4)
    const int bx  = blockIdx.x;
    const int xcd = bx & 7;
    const int sub = bx >> 3;
    const int wgs = (xcd < 4 ? xcd * 265 : 1060 + (xcd - 4) * 264) + sub;
    const int n   = wgs * 2 + wid;

    const int b   = n / (46 * 46);
    const int rem = n - b * (46 * 46);
    const int ho  = rem / 46;
    const int wo  = rem - ho * 46;

    // ---- W row fragment: w01[ic]=(W[ic][o][cq][0],[1]), w23=([2],[3]) ----
    v2f w01[8], w23[8];
    #pragma unroll
    for (int i = 0; i < 8; ++i) {
        const v4f wv = *reinterpret_cast<const v4f*>(
            &Wg[((i * 16 + o) * 4 + cq) * 4]);
        w01[i] = lo2(wv);
        w23[i] = hi2(wv);
    }

    // ---- wave-local load of this pixel's 3x3 patch (9 x 136 ch) ----
    #pragma unroll
    for (int p = 0; p < 9; ++p) {
        const int py = p / 3, px = p - py * 3;
        const float* xr = &x[(((b * 48) + ho + py) * 48 + (wo + px)) * 136];
        #pragma unroll
        for (int t = 0; t < 3; ++t) {
            const int cc = lane + t * 64;
            if (t < 2 || cc < 136) {
                const float val = xr[cc];
                const int ic = (cc * 241) >> 12;       // cc/17 for cc<136
                const int aa = cc - ic * 17;
                const int k  = p * 8 + ic;
                if (aa == 16) PT[1216 + k] = val;      // act
                else          PT[aa * 76 + k] = val;
            }
        }
    }
    asm volatile("s_waitcnt lgkmcnt(0)" ::: "memory");

    const int kT  = 64 + (lane >> 3);
    const int icT = lane >> 3;         // = kT & 7
    const int oT0 = (lane & 7) * 2;
    const int icM = lane & 7;

    // ---- round-invariant pose columns + act, hoisted (registers) ----
    float pc[16], pcT[16];
    #pragma unroll
    for (int j = 0; j < 16; ++j) pc[j]  = PT[j * 76 + lane];
    #pragma unroll
    for (int j = 0; j < 16; ++j) pcT[j] = PT[j * 76 + kT];
    const float actk = PT[1216 + lane];
    const float actT = PT[1216 + kT];
    asm volatile("s_waitcnt lgkmcnt(0)" ::: "memory");

    float lreg[16];
    #pragma unroll
    for (int j = 0; j < 16; ++j) lreg[j] = 0.f;
    float lt0 = 0.f, lt1 = 0.f;

    v2f va01[4], va23[4];              // squashed v[o][a][j], full per lane

    // dot of a pose-column (16 regs) against one G' row (4 chunks, e'=b*4+a)
    #define GDOT(P, gp, accum) do {                                          \
        const v4f b0 = (gp)[0], b1 = (gp)[1], b2 = (gp)[2], b3 = (gp)[3];    \
        v2f acc2 = {0.f, 0.f};                                               \
        acc2 = fma2(v2f{(P)[0], (P)[4]},  lo2(b0), acc2);                    \
        acc2 = fma2(v2f{(P)[8], (P)[12]}, hi2(b0), acc2);                    \
        acc2 = fma2(v2f{(P)[1], (P)[5]},  lo2(b1), acc2);                    \
        acc2 = fma2(v2f{(P)[9], (P)[13]}, hi2(b1), acc2);                    \
        acc2 = fma2(v2f{(P)[2], (P)[6]},  lo2(b2), acc2);                    \
        acc2 = fma2(v2f{(P)[10],(P)[14]}, hi2(b2), acc2);                    \
        acc2 = fma2(v2f{(P)[3], (P)[7]},  lo2(b3), acc2);                    \
        acc2 = fma2(v2f{(P)[11],(P)[15]}, hi2(b3), acc2);                    \
        accum += acc2.x + acc2.y;                                            \
    } while (0)

    #pragma unroll 1
    for (int r = 0; r < 3; ++r) {
        // ---- phase B: M[ic][a] = sum_p coup[8p+ic][o] * pose[8p+ic][a4+cq]
        const float* cb  = (r == 0) ? (PT + 1216) : (GB + o * 76);
        const float  msc = (r == 0) ? 0.0625f : 1.0f;
        v2f mac[4][4];   // [ic-pair][a]
        #pragma unroll
        for (int m = 0; m < 4; ++m)
            #pragma unroll
            for (int a = 0; a < 4; ++a) mac[m][a] = v2f{0.f, 0.f};
        #pragma unroll
        for (int p = 0; p < 9; ++p) {
            const v4f c0 = *reinterpret_cast<const v4f*>(cb + 8 * p);
            const v4f c1 = *reinterpret_cast<const v4f*>(cb + 8 * p + 4);
            #pragma unroll
            for (int a = 0; a < 4; ++a) {
                const v4f q0 = *reinterpret_cast<const v4f*>(
                    &PT[(a * 4 + cq) * 76 + 8 * p]);
                const v4f q1 = *reinterpret_cast<const v4f*>(
                    &PT[(a * 4 + cq) * 76 + 8 * p + 4]);
                mac[0][a] = fma2(lo2(c0), lo2(q0), mac[0][a]);
                mac[1][a] = fma2(hi2(c0), hi2(q0), mac[1][a]);
                mac[2][a] = fma2(lo2(c1), lo2(q1), mac[2][a]);
                mac[3][a] = fma2(hi2(c1), hi2(q1), mac[3][a]);
            }
        }
        // U[a][j] = sum_ic W[ic,o,cq,j] * M[ic][a]
        v2f U01[4], U23[4];
        #pragma unroll
        for (int a = 0; a < 4; ++a) { U01[a] = v2f{0.f,0.f}; U23[a] = v2f{0.f,0.f}; }
        #pragma unroll
        for (int m = 0; m < 4; ++m) {
            #pragma unroll
            for (int a = 0; a < 4; ++a) {
                const v2f m0 = { mac[m][a].x, mac[m][a].x };
                const v2f m1 = { mac[m][a].y, mac[m][a].y };
                U01[a] = fma2(w01[2*m],   m0, U01[a]);
                U23[a] = fma2(w23[2*m],   m0, U23[a]);
                U01[a] = fma2(w01[2*m+1], m1, U01[a]);
                U23[a] = fma2(w23[2*m+1], m1, U23[a]);
            }
        }
        // quad allreduce over cq (=b): Z[a*4+j] = s[o,a,j]
        float Z[16];
        #pragma unroll
        for (int a = 0; a < 4; ++a) {
            Z[a*4+0] = U01[a].x * msc;  Z[a*4+1] = U01[a].y * msc;
            Z[a*4+2] = U23[a].x * msc;  Z[a*4+3] = U23[a].y * msc;
        }
        #pragma unroll
        for (int j = 0; j < 16; ++j) {
            Z[j] += dpp_f<0xB1>(Z[j]);
            Z[j] += dpp_f<0x4E>(Z[j]);
        }
        // squash: fully lane-local
        float sq = 0.f;
        #pragma unroll
        for (int j = 0; j < 16; ++j) sq = fmaf(Z[j], Z[j], sq);
        const float ss = sq / ((1.f + sq) * sqrtf(sq + 1e-7f));
        #pragma unroll
        for (int a = 0; a < 4; ++a) {
            va01[a] = v2f{ Z[a*4+0] * ss, Z[a*4+1] * ss };
            va23[a] = v2f{ Z[a*4+2] * ss, Z[a*4+3] * ss };
        }

        if (r < 2) {
            // ---- G build, e'=b*4+a packing: one b128 store per ic ----
            #pragma unroll
            for (int ic = 0; ic < 8; ++ic) {
                v4f gv;
                #pragma unroll
                for (int a = 0; a < 4; ++a) {
                    const v2f h = fma2(w23[ic], va23[a], w01[ic] * va01[a]);
                    gv[a] = h.x + h.y;
                }
                *reinterpret_cast<v4f*>(&GB[g_row(o, ic) + cq * 4]) = gv;
            }
            asm volatile("s_waitcnt lgkmcnt(0)" ::: "memory");

            // ---- fused: ALL G reads first (main + tail), then CP writes ----
            float lg[16];
            #pragma unroll
            for (int oo = 0; oo < 16; ++oo) {
                const v4f* gp = reinterpret_cast<const v4f*>(&GB[g_row(oo, icM)]);
                GDOT(pc, gp, lreg[oo]);
                lg[oo] = lreg[oo];
            }
            {
                const v4f* gp0 = reinterpret_cast<const v4f*>(&GB[g_row(oT0, icT)]);
                GDOT(pcT, gp0, lt0);
                const v4f* gp1 = reinterpret_cast<const v4f*>(&GB[g_row(oT0 + 1, icT)]);
                GDOT(pcT, gp1, lt1);
            }

            // main softmax over 16 o (lane-local) -> CP writes (alias GB)
            float mx = lg[0];
            #pragma unroll
            for (int j = 1; j < 16; ++j) mx = fmaxf(mx, lg[j]);
            float sum = 0.f;
            #pragma unroll
            for (int j = 0; j < 16; ++j) { lg[j] = __expf(lg[j] - mx); sum += lg[j]; }
            const float cs = actk / sum;
            #pragma unroll
            for (int oo = 0; oo < 16; ++oo) GB[oo * 76 + lane] = lg[oo] * cs;

            // tail softmax over 16 o spread across 8-lane group (2 per lane)
            {
                float m2 = fmaxf(lt0, lt1);
                m2 = fmaxf(m2, swz<0x041F>(m2));
                m2 = fmaxf(m2, swz<0x081F>(m2));
                m2 = fmaxf(m2, swz<0x101F>(m2));
                const float e0 = __expf(lt0 - m2);
                const float e1 = __expf(lt1 - m2);
                float s2 = e0 + e1;
                s2 += swz<0x041F>(s2);
                s2 += swz<0x081F>(s2);
                s2 += swz<0x101F>(s2);
                const float csT = actT / s2;
                GB[oT0 * 76 + kT]       = e0 * csT;
                GB[(oT0 + 1) * 76 + kT] = e1 * csT;
            }
            asm volatile("s_waitcnt lgkmcnt(0)" ::: "memory");
        }
    }

    // ---- epilogue: Z (hence va) is quad-uniform, so lane (o,cq) stores
    //      atoms (a'=cq, j=0..3) as ONE b128 at base + lane*16B:
    //      a single fully-coalesced 1024B wave store ----
    {
        const v2f s01 = (cq & 2) ? ((cq & 1) ? va01[3] : va01[2])
                                 : ((cq & 1) ? va01[1] : va01[0]);
        const v2f s23 = (cq & 2) ? ((cq & 1) ? va23[3] : va23[2])
                                 : ((cq & 1) ? va23[1] : va23[0]);
        const v4f ov = { s01.x, s01.y, s23.x, s23.y };
        *reinterpret_cast<v4f*>(&out[n * 256 + o * 16 + cq * 4]) = ov;
    }
}

extern "C" void kernel_launch(void* const* d_in, const int* in_sizes, int n_in,
                              void* d_out, int out_size, void* d_ws, size_t ws_size,
                              hipStream_t stream) {
    const float* x  = (const float*)d_in[0];   // [2,48,48,136] fp32
    const float* Wt = (const float*)d_in[1];   // [8,16,4,4]    fp32
    float* outp = (float*)d_out;               // [2,46,46,16,16] fp32
    capsule_routing_kernel<<<dim3(NBLK), dim3(128), 0, stream>>>(x, Wt, outp);
}